// Round 9
// baseline (140.486 us; speedup 1.0000x reference)
//
#include <hip/hip_runtime.h>
#include <math.h>

#define BB 16
#define LL 1024
#define DD 128
#define BL (BB*LL)
#define NDEPTH 4
#define EPSF 1e-5f

typedef unsigned short u16;
typedef short bf16x8 __attribute__((ext_vector_type(8)));
typedef short bf16x4 __attribute__((ext_vector_type(4)));
typedef float f32x4 __attribute__((ext_vector_type(4)));
typedef float f32x16 __attribute__((ext_vector_type(16)));

static __device__ __forceinline__ u16 f2bf(float x) {
    unsigned u = __float_as_uint(x);
    u = u + 0x7fffu + ((u >> 16) & 1u);
    return (u16)(u >> 16);
}
// gelu with A&S 7.1.26 erf approx (|eps|<1.5e-7), fast rcp/exp
static __device__ __forceinline__ float gelu_f(float x) {
    float u = x * 0.70710678118654752f;
    float au = fabsf(u);
    float t = __builtin_amdgcn_rcpf(1.0f + 0.3275911f * au);
    float poly = ((((1.061405429f * t - 1.453152027f) * t + 1.421413741f) * t
                   - 0.284496736f) * t + 0.254829592f) * t;
    float e = __expf(-u * u);
    float erfv = 1.0f - poly * e;
    erfv = copysignf(erfv, u);
    return 0.5f * x * (1.0f + erfv);
}

// LDS layout (mega, 32-token tile) — macro layout identical to R8
#define DZ_B  0
#define S_B   15360
#define H1_B  23552
#define RST_B 39936
#define MRS_B 40064
#define LDS_TOT 40192

// ---------------------------------------------------------------- weight convert
// theta(k>=1) -> 32x32-frag-linear bf16 [slab kk][s8:8][hf:4][lane:64][8],
//   value = theta[layer][kk+1][h=hf*32+(ln&31)][d=s8*16+(ln>>5)*8+j] * ln_g[d]/sqrt2
// w1 -> [layer][f:16][c:4][lane][8]; w2 -> [layer][f:8][c:8][lane][8]  (16x16 frags)
#define N_TH (4*15*16384)
#define N_W1 (4*32768)
#define N_W2 (4*32768)
__global__ __launch_bounds__(256) void cvt_kernel(const float* __restrict__ theta,
        const float* __restrict__ fc1w, const float* __restrict__ fc2w,
        const float* __restrict__ ln_g,
        u16* __restrict__ thf, u16* __restrict__ w1f, u16* __restrict__ w2f) {
    int o = blockIdx.x * 256 + threadIdx.x;
    if (o < N_TH) {
        int j = o & 7, ln = (o >> 3) & 63, hf = (o >> 9) & 3, s8 = (o >> 11) & 7;
        int slab = o >> 14;
        int layer = slab / 15, kk = slab - layer * 15;
        int h = hf * 32 + (ln & 31), d = s8 * 16 + (ln >> 5) * 8 + j;
        float v = theta[(((size_t)layer * 16 + kk + 1) * 128 + h) * 128 + d];
        v *= ln_g[layer * 128 + d] * 0.70710678118654752f;
        thf[o] = f2bf(v);
    } else if (o < N_TH + N_W1) {
        int o2 = o - N_TH;
        int j = o2 & 7, ln = (o2 >> 3) & 63, c = (o2 >> 9) & 3, f = (o2 >> 11) & 15;
        int layer = o2 >> 15;
        int m = f * 16 + (ln & 15), d = 32 * c + 8 * (ln >> 4) + j;
        w1f[o2] = f2bf(fc1w[(size_t)layer * 32768 + m * 128 + d]);
    } else if (o < N_TH + N_W1 + N_W2) {
        int o2 = o - (N_TH + N_W1);
        int j = o2 & 7, ln = (o2 >> 3) & 63, c = (o2 >> 9) & 7, f = (o2 >> 12) & 7;
        int layer = o2 >> 15;
        int d = f * 16 + (ln & 15), m = 32 * c + 8 * (ln >> 4) + j;
        w2f[o2] = f2bf(fc2w[(size_t)layer * 32768 + d * 256 + m]);
    }
}

// ---------------------------------------------------------------- prep0: lift + LN-stats + partials
__global__ __launch_bounds__(512) void prep0_kernel(const float* __restrict__ x,
        const float* __restrict__ lw, const float* __restrict__ lb,
        float* __restrict__ H, float2* __restrict__ stats,
        float* __restrict__ P1p, float* __restrict__ P2p) {
    __shared__ char lds[16384 + 256];
    float* rst = (float*)(lds + 16384);
    float* mrs = (float*)(lds + 16384 + 128);
    int b = blockIdx.y, nblk = blockIdx.x, t0 = nblk * 32, tid = threadIdx.x;

    #pragma unroll
    for (int it = 0; it < 2; ++it) {
        int idx = it * 512 + tid;
        int r = idx >> 5, d0 = (idx & 31) * 4;
        int l = t0 + r;
        float x0 = x[(size_t)b * 3072 + l];
        float x1 = x[(size_t)b * 3072 + 1024 + l];
        float x2 = x[(size_t)b * 3072 + 2048 + l];
        float coord = (float)l * (1.0f / 1023.0f);
        f32x4 hv;
        #pragma unroll
        for (int q = 0; q < 4; ++q) {
            int d = d0 + q;
            float4 w = *(const float4*)(lw + d * 4);
            hv[q] = lb[d] + w.x * x0 + w.y * x1 + w.z * x2 + w.w * coord;
        }
        *(f32x4*)(H + ((size_t)b * 1024 + l) * 128 + d0) = hv;
        int byte = r * 512 + ((d0 * 4) ^ ((r & 7) << 4));
        *(f32x4*)(lds + byte) = hv;
    }
    __syncthreads();
    {
        int t = tid >> 4, q = tid & 15;
        float s = 0.f, sq = 0.f;
        #pragma unroll
        for (int dd = 0; dd < 8; dd += 4) {
            int d = q * 8 + dd;
            int byte = t * 512 + ((d * 4) ^ ((t & 7) << 4));
            f32x4 v = *(const f32x4*)(lds + byte);
            s += v[0] + v[1] + v[2] + v[3];
            sq += v[0]*v[0] + v[1]*v[1] + v[2]*v[2] + v[3]*v[3];
        }
        #pragma unroll
        for (int o = 1; o < 16; o <<= 1) {
            s += __shfl_xor(s, o, 64); sq += __shfl_xor(sq, o, 64);
        }
        if (q == 0) {
            float mu = s * (1.f / 128.f);
            float var = sq * (1.f / 128.f) - mu * mu;
            float rs = rsqrtf(var + EPSF);
            stats[(size_t)b * 1024 + t0 + t] = make_float2(mu, rs);
            rst[t] = rs; mrs[t] = mu * rs;
        }
    }
    __syncthreads();
    if (tid < 128) {
        float s = 0.f;
        #pragma unroll 8
        for (int t = 0; t < 32; ++t) {
            int byte = t * 512 + ((tid * 4) ^ ((t & 7) << 4));
            s += *(const float*)(lds + byte) * rst[t];
        }
        P1p[((size_t)b * 32 + nblk) * 128 + tid] = s;
    } else if (tid == 128) {
        float s = 0.f;
        for (int t = 0; t < 32; ++t) s += mrs[t];
        P2p[b * 32 + nblk] = s;
    }
}

// ---------------------------------------------------------------- C[b,h] (k=0 Haar row), grid (16 b, 8 hc)
__global__ __launch_bounds__(128) void c_kernel(const float* __restrict__ theta0,
        const float* __restrict__ P1p, const float* __restrict__ P2p,
        const float* __restrict__ lng, const float* __restrict__ lnb,
        float* __restrict__ C) {
    __shared__ float zsum[128];
    int b = blockIdx.x, hc = blockIdx.y, tid = threadIdx.x;
    float s = 0.f;
    #pragma unroll 8
    for (int j = 0; j < 32; ++j) s += P1p[((size_t)b * 32 + j) * 128 + tid];
    float p2 = 0.f;
    #pragma unroll 8
    for (int j = 0; j < 32; ++j) p2 += P2p[b * 32 + j];
    zsum[tid] = lng[tid] * (s - p2) + 1024.0f * lnb[tid];
    __syncthreads();
    int h = hc * 16 + (tid >> 3), q = tid & 7;
    const float* th = theta0 + h * 128 + q * 16;
    float acc = 0.f;
    #pragma unroll
    for (int d = 0; d < 16; d += 4) {
        float4 tv = *(const float4*)(th + d);
        acc += tv.x * zsum[q*16 + d] + tv.y * zsum[q*16 + d + 1]
             + tv.z * zsum[q*16 + d + 2] + tv.w * zsum[q*16 + d + 3];
    }
    acc += __shfl_xor(acc, 1, 64);
    acc += __shfl_xor(acc, 2, 64);
    acc += __shfl_xor(acc, 4, 64);
    if (q == 0) C[b * 128 + h] = acc * (1.0f / 32.0f);
}

// ---------------------------------------------------------------- mega (R8 macro-structure; Phase B on 32x32x16 MFMA)
// 512 threads (8 waves), 32-token tile, grid (32, 16) = 512 blocks = 2/CU.
// Phase B waves = hf(4) x ks(2): K-split halves, combine via H1 region.
template<int LAST>
__global__ __launch_bounds__(512, 4) void mega_kernel(
        const float* __restrict__ Hin, const float2* __restrict__ stin,
        const u16* __restrict__ thf, const float* __restrict__ Cb_,
        const u16* __restrict__ w1f, const float* __restrict__ b1,
        const u16* __restrict__ w2f, const float* __restrict__ b2,
        float* __restrict__ Hout, float2* __restrict__ stout,
        float* __restrict__ P1p, float* __restrict__ P2p,
        const float* __restrict__ hwp, const float* __restrict__ hbp,
        float* __restrict__ out) {
    __shared__ char lds[LDS_TOT];
    int b = blockIdx.y, nblk = blockIdx.x, n0 = nblk * 32, tid = threadIdx.x;

    // ---- Phase A: dz staging (60 halo rows); ln_g & 1/sqrt2 folded into theta.
    // Swizzle (r&15)<<4 — Phase B's 32-row B-frag walk needs the wider spread.
    const float* Hb = Hin + (size_t)b * 1024 * 128;
    const float2* stb = stin + (size_t)b * 1024;
    for (int c = tid; c < 60 * 16; c += 512) {
        int r = c >> 4, d0 = (c & 15) * 8;
        int gr = (n0 + r) & 1023, g1 = (n0 + r + 1) & 1023;
        const float* ha = Hb + (size_t)gr * 128 + d0;
        const float* hc = Hb + (size_t)g1 * 128 + d0;
        float2 sa = stb[gr], sb = stb[g1];
        u16 tmp[8];
        #pragma unroll
        for (int j = 0; j < 8; ++j) {
            float za = (ha[j] - sa.x) * sa.y;
            float zc = (hc[j] - sb.x) * sb.y;
            tmp[j] = f2bf(za - zc);
        }
        int byte = r * 256 + ((d0 * 2) ^ ((r & 15) << 4));
        *(bf16x8*)(lds + byte) = *(bf16x8*)tmp;
    }
    __syncthreads();

    int wave = tid >> 6, lane = tid & 63;
    int lm = lane & 15, lk = (lane >> 4) * 8;
    f32x4 zero4 = {0.f, 0.f, 0.f, 0.f};

    // ---- Phase B: S via 32x32x16 MFMA. wave = hf(4) x ks(2). Theta read ONCE per block.
    int hf = wave & 3, ks = wave >> 2;
    f32x16 accA = {0.f}, accB = {0.f};
    {
        const u16* thl = thf + (size_t)lane * 8;
        int s0 = ks * 60;
        int l31 = lane & 31, lh = (lane >> 5) * 8;
        #pragma unroll 4
        for (int s = s0; s < s0 + 60; s += 2) {
            {
                int kk = s >> 3, s8 = s & 7;
                bf16x8 afr = *(const bf16x8*)(thl + ((size_t)((kk * 8 + s8) * 4 + hf) << 9));
                int trow = l31 + 2 * kk;
                int d0 = s8 * 16 + lh;
                int byte = trow * 256 + ((d0 * 2) ^ ((trow & 15) << 4));
                bf16x8 bfr = *(const bf16x8*)(lds + byte);
                accA = __builtin_amdgcn_mfma_f32_32x32x16_bf16(afr, bfr, accA, 0, 0, 0);
            }
            {
                int s1 = s + 1;
                int kk = s1 >> 3, s8 = s1 & 7;
                bf16x8 afr = *(const bf16x8*)(thl + ((size_t)((kk * 8 + s8) * 4 + hf) << 9));
                int trow = l31 + 2 * kk;
                int d0 = s8 * 16 + lh;
                int byte = trow * 256 + ((d0 * 2) ^ ((trow & 15) << 4));
                bf16x8 bfr = *(const bf16x8*)(lds + byte);
                accB = __builtin_amdgcn_mfma_f32_32x32x16_bf16(afr, bfr, accB, 0, 0, 0);
            }
        }
    }
    // ---- ks=1 waves dump partials (4KB/wave) into H1 region
    if (ks) {
        #pragma unroll
        for (int g = 0; g < 4; ++g) {
            f32x4 p;
            #pragma unroll
            for (int r = 0; r < 4; ++r) p[r] = accA[4*g + r] + accB[4*g + r];
            *(f32x4*)(lds + H1_B + hf * 4096 + g * 1024 + lane * 16) = p;
        }
    }
    __syncthreads();

    // ---- Phase C: ks=0 waves combine + C-epilogue -> S tile (bf16)
    if (!ks) {
        const float* Crow = Cb_ + b * 128;
        int t = lane & 31;
        #pragma unroll
        for (int g = 0; g < 4; ++g) {
            f32x4 p = *(const f32x4*)(lds + H1_B + hf * 4096 + g * 1024 + lane * 16);
            int h0 = hf * 32 + g * 8 + 4 * (lane >> 5);
            f32x4 cv = *(const f32x4*)(Crow + h0);
            u16 o[4];
            #pragma unroll
            for (int r = 0; r < 4; ++r)
                o[r] = f2bf(accA[4*g + r] + accB[4*g + r] + p[r] + cv[r]);
            int byte = S_B + t * 256 + ((h0 * 2) ^ ((t & 7) << 4));
            *(bf16x4*)(lds + byte) = *(bf16x4*)o;
        }
    }
    __syncthreads();

    // ---- Phase D: fc1 (A from global w1f) + GELU -> H1   (unchanged from R8)
    {
        f32x4 acc1[2][2];
        #pragma unroll
        for (int mt = 0; mt < 2; ++mt)
            #pragma unroll
            for (int nt = 0; nt < 2; ++nt) acc1[mt][nt] = zero4;
        const u16* w1l = w1f + (size_t)lane * 8;
        #pragma unroll
        for (int c4 = 0; c4 < 4; ++c4) {
            bf16x8 afr[2], bfr[2];
            #pragma unroll
            for (int mt = 0; mt < 2; ++mt)
                afr[mt] = *(const bf16x8*)(w1l + ((size_t)((wave * 2 + mt) * 4 + c4) << 9));
            #pragma unroll
            for (int nt = 0; nt < 2; ++nt) {
                int tl = nt * 16 + lm;
                int byte = S_B + tl * 256 + (((c4 * 32 + lk) * 2) ^ ((tl & 7) << 4));
                bfr[nt] = *(const bf16x8*)(lds + byte);
            }
            #pragma unroll
            for (int mt = 0; mt < 2; ++mt)
                #pragma unroll
                for (int nt = 0; nt < 2; ++nt)
                    acc1[mt][nt] = __builtin_amdgcn_mfma_f32_16x16x32_bf16(
                        afr[mt], bfr[nt], acc1[mt][nt], 0, 0, 0);
        }
        #pragma unroll
        for (int mt = 0; mt < 2; ++mt) {
            int mo = wave * 32 + mt * 16 + (lane >> 4) * 4;
            f32x4 bb4 = *(const f32x4*)(b1 + mo);
            #pragma unroll
            for (int nt = 0; nt < 2; ++nt) {
                int tl = nt * 16 + lm;
                u16 o[4];
                #pragma unroll
                for (int r = 0; r < 4; ++r)
                    o[r] = f2bf(gelu_f(acc1[mt][nt][r] + bb4[r]));
                int byte = H1_B + tl * 512 + ((mo * 2) ^ ((tl & 7) << 4));
                *(bf16x4*)(lds + byte) = *(bf16x4*)o;
            }
        }
    }
    __syncthreads();

    // ---- Phase F: fc2 (A from global w2f)
    f32x4 acc2[2] = {zero4, zero4};
    {
        const u16* w2l = w2f + (size_t)lane * 8;
        #pragma unroll
        for (int c8 = 0; c8 < 8; ++c8) {
            bf16x8 afr = *(const bf16x8*)(w2l + ((size_t)(wave * 8 + c8) << 9));
            #pragma unroll
            for (int nt = 0; nt < 2; ++nt) {
                int tl = nt * 16 + lm;
                int byte = H1_B + tl * 512 + (((c8 * 32 + lk) * 2) ^ ((tl & 7) << 4));
                bf16x8 bfr = *(const bf16x8*)(lds + byte);
                acc2[nt] = __builtin_amdgcn_mfma_f32_16x16x32_bf16(afr, bfr, acc2[nt], 0, 0, 0);
            }
        }
    }
    __syncthreads();

    // ---- Phase G: fc2 result f32 -> Ht [t][d] (reuse H1 region)
    {
        int dbase = wave * 16 + (lane >> 4) * 4;
        #pragma unroll
        for (int nt = 0; nt < 2; ++nt) {
            int tl = nt * 16 + lm;
            int byte = H1_B + tl * 512 + ((dbase * 4) ^ ((tl & 7) << 4));
            *(f32x4*)(lds + byte) = acc2[nt];
        }
    }
    __syncthreads();

    // ---- Phase H: residual writeback (+ head if LAST)
    {
        const float* Hrow = Hin + ((size_t)b * 1024 + n0) * 128;
        float* Horow = Hout + ((size_t)b * 1024 + n0) * 128;
        #pragma unroll
        for (int it = 0; it < 2; ++it) {
            int idx = it * 512 + tid;
            int r = idx >> 5, d0 = (idx & 31) * 4;
            int byte = H1_B + r * 512 + ((d0 * 4) ^ ((r & 7) << 4));
            f32x4 v = *(const f32x4*)(lds + byte);
            f32x4 bb = *(const f32x4*)(b2 + d0);
            f32x4 hv = *(const f32x4*)(Hrow + (size_t)r * 128 + d0);
            hv = hv + v + bb;
            if (LAST) {
                f32x4 wv = *(const f32x4*)(hwp + d0);
                float s = hv[0]*wv[0] + hv[1]*wv[1] + hv[2]*wv[2] + hv[3]*wv[3];
                #pragma unroll
                for (int o = 1; o < 32; o <<= 1) s += __shfl_xor(s, o, 64);
                if ((lane & 31) == 0) out[(size_t)b * 1024 + n0 + r] = s + hbp[0];
            } else {
                *(f32x4*)(Horow + (size_t)r * 128 + d0) = hv;
                *(f32x4*)(lds + byte) = hv;
            }
        }
    }
    if (!LAST) {
        __syncthreads();
        // ---- Phase I: next-layer LN stats
        float* rst = (float*)(lds + RST_B);
        float* mrs = (float*)(lds + MRS_B);
        {
            int t = tid >> 4, q = tid & 15;
            float s = 0.f, sq = 0.f;
            #pragma unroll
            for (int dd = 0; dd < 8; dd += 4) {
                int d = q * 8 + dd;
                int byte = H1_B + t * 512 + ((d * 4) ^ ((t & 7) << 4));
                f32x4 v = *(const f32x4*)(lds + byte);
                s += v[0] + v[1] + v[2] + v[3];
                sq += v[0]*v[0] + v[1]*v[1] + v[2]*v[2] + v[3]*v[3];
            }
            #pragma unroll
            for (int o = 1; o < 16; o <<= 1) {
                s += __shfl_xor(s, o, 64); sq += __shfl_xor(sq, o, 64);
            }
            if (q == 0) {
                float mu = s * (1.f / 128.f);
                float var = sq * (1.f / 128.f) - mu * mu;
                float rs = rsqrtf(var + EPSF);
                stout[(size_t)b * 1024 + n0 + t] = make_float2(mu, rs);
                rst[t] = rs; mrs[t] = mu * rs;
            }
        }
        __syncthreads();
        // ---- Phase J: partial column sums for next-layer C
        if (tid < 128) {
            float s = 0.f;
            #pragma unroll 8
            for (int t = 0; t < 32; ++t) {
                int byte = H1_B + t * 512 + ((tid * 4) ^ ((t & 7) << 4));
                s += *(const float*)(lds + byte) * rst[t];
            }
            P1p[((size_t)b * 32 + nblk) * 128 + tid] = s;
        } else if (tid == 128) {
            float s = 0.f;
            for (int t = 0; t < 32; ++t) s += mrs[t];
            P2p[b * 32 + nblk] = s;
        }
    }
}

// ----------------------------------------------------------------
extern "C" void kernel_launch(void* const* d_in, const int* in_sizes, int n_in,
                              void* d_out, int out_size, void* d_ws, size_t ws_size,
                              hipStream_t stream) {
    const float* x     = (const float*)d_in[0];
    const float* lw    = (const float*)d_in[1];
    const float* lb    = (const float*)d_in[2];
    // d_in[3] = Phi_f — analytically eliminated (Haar top-16 = const + finest 2-tap wavelets)
    const float* theta = (const float*)d_in[4];
    const float* ln_g  = (const float*)d_in[5];
    const float* ln_b  = (const float*)d_in[6];
    const float* fc1w  = (const float*)d_in[7];
    const float* fc1b  = (const float*)d_in[8];
    const float* fc2w  = (const float*)d_in[9];
    const float* fc2b  = (const float*)d_in[10];
    const float* hw    = (const float*)d_in[11];
    const float* hb    = (const float*)d_in[12];

    float* ws = (float*)d_ws;
    float* H_A = ws;                                   // 2M f32
    float* H_B = H_A + (size_t)BL * DD;                // 2M f32
    float2* st_A = (float2*)(H_B + (size_t)BL * DD);   // 16384 float2
    float2* st_B = st_A + BL;
    float* P1p = (float*)(st_B + BL);                  // 16*32*128
    float* P2p = P1p + 16 * 32 * 128;                  // 512
    float* Cb  = P2p + 512;                            // 2048
    u16* thf = (u16*)(Cb + 2048);                      // N_TH
    u16* w1f = thf + N_TH;                             // N_W1
    u16* w2f = w1f + N_W1;                             // N_W2

    cvt_kernel<<<(N_TH + N_W1 + N_W2) / 256, 256, 0, stream>>>(
        theta, fc1w, fc2w, ln_g, thf, w1f, w2f);
    prep0_kernel<<<dim3(32, 16), 512, 0, stream>>>(x, lw, lb, H_A, st_A, P1p, P2p);

    float* Hi = H_A; float* Ho = H_B;
    float2* sti = st_A; float2* sto = st_B;
    for (int i = 0; i < NDEPTH; ++i) {
        c_kernel<<<dim3(16, 8), 128, 0, stream>>>(theta + (size_t)i * 16 * 16384, P1p, P2p,
                                                  ln_g + i * 128, ln_b + i * 128, Cb);
        if (i < NDEPTH - 1) {
            mega_kernel<0><<<dim3(32, 16), 512, 0, stream>>>(
                Hi, sti,
                thf + (size_t)i * 15 * 16384, Cb,
                w1f + (size_t)i * 32768, fc1b + i * 256,
                w2f + (size_t)i * 32768, fc2b + i * 128,
                Ho, sto, P1p, P2p, hw, hb, (float*)d_out);
        } else {
            mega_kernel<1><<<dim3(32, 16), 512, 0, stream>>>(
                Hi, sti,
                thf + (size_t)i * 15 * 16384, Cb,
                w1f + (size_t)i * 32768, fc1b + i * 256,
                w2f + (size_t)i * 32768, fc2b + i * 128,
                Ho, sto, P1p, P2p, hw, hb, (float*)d_out);
        }
        float* tH = Hi; Hi = Ho; Ho = tH;
        float2* tS = sti; sti = sto; sto = tS;
    }
}